// Round 7
// baseline (234.581 us; speedup 1.0000x reference)
//
#include <hip/hip_runtime.h>
#include <hip/hip_bf16.h>

// SubjectLayers: out[b,d] = sum_c x[b,c] * W[idx[b],c,d] + bias[idx[b],d]
// B=512, C=D=1024, 32 subjects, fp32.
//
// R4: waves sharing W = 4x redundant VMEM issue (10 B/cy/CU ceiling).
// R5: waves split C (disjoint W) -> gemm ~55-65 us. Remaining waste:
//     chunk splits (ROWS=16, mean n=16 -> ~48 chunks) re-read W: 192 MB issued.
// R6: ROWS_PER_CHUNK=24 (P(split)~2% -> ~33 chunks -> 132 MB issued, 21 us
//     floor); drop partials/reduce kernel: init_bias + block-level atomicAdd.
// (R6 resubmit: previous attempt hit GPUAcquisitionTimeout, never measured.)

typedef float f4v __attribute__((ext_vector_type(4)));

#define N_SUBJ 32
#define B_ROWS 512
#define IN_CH_K 1024
#define OUT_CH_K 1024
#define RPC 24                 // rows per chunk
#define MAX_CHUNKS 64          // worst case sum ceil(n_s/24) <= 53
#define CSEGS 4
#define CSEG 256               // block c-tile; 4 waves x 64 c-rows
#define WSLICE 64
#define DTILES 4
#define DTILE 256
#define XPAD 28                // xst row stride: 16B-aligned rows (28*4=112)

// d_ws: int32 [0]=n_chunks; [1..1+3*64) entries {s,start,cnt}; [256..768) perm
#define ENT_OFF 1
#define PERM_OFF 256

__global__ __launch_bounds__(512) void build_groups(
    const int* __restrict__ idx, int* __restrict__ ws)
{
    __shared__ int counts[N_SUBJ];
    __shared__ int offs[N_SUBJ];
    __shared__ int cursor[N_SUBJ];
    const int t = threadIdx.x;
    if (t < N_SUBJ) counts[t] = 0;
    __syncthreads();
    const int s = idx[t] & (N_SUBJ - 1);
    atomicAdd(&counts[s], 1);
    __syncthreads();
    if (t == 0) {
        int acc = 0, nch = 0;
        for (int i = 0; i < N_SUBJ; ++i) {
            offs[i] = acc;
            cursor[i] = acc;
            acc += counts[i];
        }
        for (int i = 0; i < N_SUBJ; ++i) {
            for (int st = 0; st < counts[i]; st += RPC) {
                int c = counts[i] - st;
                if (c > RPC) c = RPC;
                ws[ENT_OFF + nch * 3 + 0] = i;
                ws[ENT_OFF + nch * 3 + 1] = offs[i] + st;
                ws[ENT_OFF + nch * 3 + 2] = c;
                ++nch;
            }
        }
        ws[0] = nch;
    }
    __syncthreads();
    const int pos = atomicAdd(&cursor[s], 1);
    ws[PERM_OFF + pos] = t;
}

// out[b,:] = bias[idx[b],:]  (gemm then atomicAdds partial sums)
__global__ __launch_bounds__(256) void init_bias(
    const int* __restrict__ idx, const float* __restrict__ bias,
    float* __restrict__ out)
{
    const int b = blockIdx.x;
    const int s = idx[b];
    const int d = threadIdx.x * 4;
    *(float4*)&out[(size_t)b * OUT_CH_K + d] =
        *(const float4*)&bias[(size_t)s * OUT_CH_K + d];
}

#define GLOAD(dst, ptr) \
    asm volatile("global_load_dwordx4 %0, %1, off" : "=v"(dst) : "v"(ptr))
#define WAIT_VM(n) do { \
    asm volatile("s_waitcnt vmcnt(" #n ")" ::: "memory"); \
    __builtin_amdgcn_sched_barrier(0); } while (0)

// One c-row: w (f4v, lane's 4 d) x 24 broadcast x values
#define CSTEP(wreg, cidx) { \
    const float4 x0 = ((const float4*)&xst[cidx][0])[0]; \
    const float4 x1 = ((const float4*)&xst[cidx][0])[1]; \
    const float4 x2 = ((const float4*)&xst[cidx][0])[2]; \
    const float4 x3 = ((const float4*)&xst[cidx][0])[3]; \
    const float4 x4 = ((const float4*)&xst[cidx][0])[4]; \
    const float4 x5 = ((const float4*)&xst[cidx][0])[5]; \
    acc[ 0] += wreg * x0.x;  acc[ 1] += wreg * x0.y; \
    acc[ 2] += wreg * x0.z;  acc[ 3] += wreg * x0.w; \
    acc[ 4] += wreg * x1.x;  acc[ 5] += wreg * x1.y; \
    acc[ 6] += wreg * x1.z;  acc[ 7] += wreg * x1.w; \
    acc[ 8] += wreg * x2.x;  acc[ 9] += wreg * x2.y; \
    acc[10] += wreg * x2.z;  acc[11] += wreg * x2.w; \
    acc[12] += wreg * x3.x;  acc[13] += wreg * x3.y; \
    acc[14] += wreg * x3.z;  acc[15] += wreg * x3.w; \
    acc[16] += wreg * x4.x;  acc[17] += wreg * x4.y; \
    acc[18] += wreg * x4.z;  acc[19] += wreg * x4.w; \
    acc[20] += wreg * x5.x;  acc[21] += wreg * x5.y; \
    acc[22] += wreg * x5.z;  acc[23] += wreg * x5.w; }

// grid (chunk, cseg, dtile); 4 waves split the c-tile (disjoint W streams),
// each accumulates all 24 rows; LDS phased combine; atomicAdd into out.
__global__ __launch_bounds__(256, 2) void subject_gemm(
    const float* __restrict__ x, const float* __restrict__ W,
    const int* __restrict__ ws, float* __restrict__ out)
{
    const int chunk = blockIdx.x;
    if (chunk >= ws[0]) return;
    const int s     = ws[ENT_OFF + chunk * 3 + 0];
    const int start = ws[ENT_OFF + chunk * 3 + 1];
    const int cnt   = ws[ENT_OFF + chunk * 3 + 2];
    const int cbase = blockIdx.y * CSEG;
    const int dbase = blockIdx.z * DTILE;

    __shared__ float xst[CSEG][XPAD];            // transposed x tile [c][row]
    __shared__ int rowidx[RPC];

    const int t = threadIdx.x;
    if (t < RPC)
        rowidx[t] = (t < cnt) ? ws[PERM_OFF + start + t] : -1;
    __syncthreads();

    #pragma unroll
    for (int r = 0; r < RPC; ++r) {
        const int row = rowidx[r];
        xst[t][r] = (row >= 0) ? x[(size_t)row * IN_CH_K + cbase + t] : 0.0f;
    }
    __syncthreads();   // drains vmcnt -> asm counts below deterministic

    const int lane = t & 63;
    const int wave = t >> 6;
    const int cs   = wave * WSLICE;
    const int d    = dbase + lane * 4;
    const float* wp = W + (size_t)s * (IN_CH_K * OUT_CH_K)
                        + (size_t)(cbase + cs) * OUT_CH_K + d;

    f4v acc[RPC];
    #pragma unroll
    for (int r = 0; r < RPC; ++r) acc[r] = (f4v){0.f, 0.f, 0.f, 0.f};
    f4v wa0, wa1, wa2, wa3, wb0, wb1, wb2, wb3;

    GLOAD(wa0, wp + 0 * OUT_CH_K);
    GLOAD(wa1, wp + 1 * OUT_CH_K);
    GLOAD(wa2, wp + 2 * OUT_CH_K);
    GLOAD(wa3, wp + 3 * OUT_CH_K);
    GLOAD(wb0, wp + 4 * OUT_CH_K);
    GLOAD(wb1, wp + 5 * OUT_CH_K);
    GLOAD(wb2, wp + 6 * OUT_CH_K);
    GLOAD(wb3, wp + 7 * OUT_CH_K);

    #pragma unroll 1
    for (int cb = 0; cb < WSLICE - 8; cb += 8) {
        WAIT_VM(4);                              // A landed, B in flight
        CSTEP(wa0, cs + cb + 0)
        CSTEP(wa1, cs + cb + 1)
        CSTEP(wa2, cs + cb + 2)
        CSTEP(wa3, cs + cb + 3)
        const float* wn = wp + (size_t)(cb + 8) * OUT_CH_K;
        GLOAD(wa0, wn + 0 * OUT_CH_K);
        GLOAD(wa1, wn + 1 * OUT_CH_K);
        GLOAD(wa2, wn + 2 * OUT_CH_K);
        GLOAD(wa3, wn + 3 * OUT_CH_K);
        WAIT_VM(4);                              // B landed, next-A in flight
        CSTEP(wb0, cs + cb + 4)
        CSTEP(wb1, cs + cb + 5)
        CSTEP(wb2, cs + cb + 6)
        CSTEP(wb3, cs + cb + 7)
        GLOAD(wb0, wn + 4 * OUT_CH_K);
        GLOAD(wb1, wn + 5 * OUT_CH_K);
        GLOAD(wb2, wn + 6 * OUT_CH_K);
        GLOAD(wb3, wn + 7 * OUT_CH_K);
    }
    {   // epilogue: cb = WSLICE-8
        const int cb = WSLICE - 8;
        WAIT_VM(4);
        CSTEP(wa0, cs + cb + 0)
        CSTEP(wa1, cs + cb + 1)
        CSTEP(wa2, cs + cb + 2)
        CSTEP(wa3, cs + cb + 3)
        WAIT_VM(0);
        CSTEP(wb0, cs + cb + 4)
        CSTEP(wb1, cs + cb + 5)
        CSTEP(wb2, cs + cb + 6)
        CSTEP(wb3, cs + cb + 7)
    }

    // ---- cross-wave combine in LDS (reuse xst: 24x256x4 = 24 KB <= 28 KB) ----
    __syncthreads();
    float (*obuf)[DTILE] = (float(*)[DTILE])&xst[0][0];
    if (wave == 0) {
        #pragma unroll
        for (int r = 0; r < RPC; ++r)
            *(f4v*)&obuf[r][lane * 4] = acc[r];
    }
    __syncthreads();
    #pragma unroll
    for (int w = 1; w < 4; ++w) {
        if (wave == w) {
            #pragma unroll
            for (int r = 0; r < RPC; ++r) {
                f4v v = *(const f4v*)&obuf[r][lane * 4];
                *(f4v*)&obuf[r][lane * 4] = v + acc[r];
            }
        }
        __syncthreads();
    }

    // wave w atomically adds rows 6w..6w+5 into out (bias pre-seeded)
    #pragma unroll
    for (int i = 0; i < 6; ++i) {
        const int r = wave * 6 + i;
        const int row = rowidx[r];
        if (row >= 0) {
            const f4v v = *(const f4v*)&obuf[r][lane * 4];
            float* o = &out[(size_t)row * OUT_CH_K + d];
            atomicAdd(o + 0, v.x); atomicAdd(o + 1, v.y);
            atomicAdd(o + 2, v.z); atomicAdd(o + 3, v.w);
        }
    }
}

extern "C" void kernel_launch(void* const* d_in, const int* in_sizes, int n_in,
                              void* d_out, int out_size, void* d_ws, size_t ws_size,
                              hipStream_t stream) {
    const float* x    = (const float*)d_in[0];
    const int*   idx  = (const int*)d_in[1];
    const float* W    = (const float*)d_in[2];
    const float* bias = (const float*)d_in[3];
    float* out = (float*)d_out;
    int* ws = (int*)d_ws;

    build_groups<<<1, 512, 0, stream>>>(idx, ws);
    init_bias<<<B_ROWS, 256, 0, stream>>>(idx, bias, out);

    dim3 grid(MAX_CHUNKS, CSEGS, DTILES);  // (64,4,4); ~528 active blocks
    subject_gemm<<<grid, 256, 0, stream>>>(x, W, ws, out);
}

// Round 8
// 233.299 us; speedup vs baseline: 1.0055x; 1.0055x over previous
//
#include <hip/hip_runtime.h>
#include <hip/hip_bf16.h>

// SubjectLayers: out[b,d] = sum_c x[b,c] * W[idx[b],c,d] + bias[idx[b],d]
// B=512, C=D=1024, 32 subjects, fp32.
//
// Evidence trail: issued-VMEM rate ~ waves/CU (R2: 9w->5.9TB/s, R4: 12w->6.2,
// R7: 5.5w->1.6) -> latency-bound; need ~16 waves/CU with disjoint-W traffic.
// R8: CSEGS=8 (1056 active blocks, 4 blocks/CU), RPC=24 (33 chunks, 132 MB
// issued), streaming partials in ws (no atomic write amplification) + reduce.

typedef float f4v __attribute__((ext_vector_type(4)));

#define N_SUBJ 32
#define B_ROWS 512
#define IN_CH_K 1024
#define OUT_CH_K 1024
#define RPC 24                 // rows per chunk
#define MAX_CHUNKS 64          // worst case sum ceil(n_s/24) <= 53
#define CSEGS 8
#define CSEG 128               // block c-tile; 4 waves x 32 c-rows
#define WSLICE 32
#define DTILES 4
#define DTILE 256
#define XPAD 28                // xst row stride (floats)

// d_ws: int32 [0]=n_chunks; [1..193) entries {s,start,cnt}; [256..768) perm;
//       float [1024...) partials: CSEGS x 512 x 1024 (16 MB; ws is ~512 MB)
#define ENT_OFF 1
#define PERM_OFF 256
#define PART_OFF_F 1024

__global__ __launch_bounds__(512) void build_groups(
    const int* __restrict__ idx, int* __restrict__ ws)
{
    __shared__ int counts[N_SUBJ];
    __shared__ int offs[N_SUBJ];
    __shared__ int cursor[N_SUBJ];
    const int t = threadIdx.x;
    if (t < N_SUBJ) counts[t] = 0;
    __syncthreads();
    const int s = idx[t] & (N_SUBJ - 1);
    atomicAdd(&counts[s], 1);
    __syncthreads();
    if (t == 0) {
        int acc = 0, nch = 0;
        for (int i = 0; i < N_SUBJ; ++i) {
            offs[i] = acc;
            cursor[i] = acc;
            acc += counts[i];
        }
        for (int i = 0; i < N_SUBJ; ++i) {
            for (int st = 0; st < counts[i]; st += RPC) {
                int c = counts[i] - st;
                if (c > RPC) c = RPC;
                ws[ENT_OFF + nch * 3 + 0] = i;
                ws[ENT_OFF + nch * 3 + 1] = offs[i] + st;
                ws[ENT_OFF + nch * 3 + 2] = c;
                ++nch;
            }
        }
        ws[0] = nch;
    }
    __syncthreads();
    const int pos = atomicAdd(&cursor[s], 1);
    ws[PERM_OFF + pos] = t;
}

#define GLOAD(dst, ptr) \
    asm volatile("global_load_dwordx4 %0, %1, off" : "=v"(dst) : "v"(ptr))
#define WAIT_VM(n) do { \
    asm volatile("s_waitcnt vmcnt(" #n ")" ::: "memory"); \
    __builtin_amdgcn_sched_barrier(0); } while (0)

// One c-row: w (f4v = lane's 4 d) x 24 broadcast x values
#define CSTEP(wreg, cidx) { \
    const float4 x0 = ((const float4*)&xst[cidx][0])[0]; \
    const float4 x1 = ((const float4*)&xst[cidx][0])[1]; \
    const float4 x2 = ((const float4*)&xst[cidx][0])[2]; \
    const float4 x3 = ((const float4*)&xst[cidx][0])[3]; \
    const float4 x4 = ((const float4*)&xst[cidx][0])[4]; \
    const float4 x5 = ((const float4*)&xst[cidx][0])[5]; \
    acc[ 0] += wreg * x0.x;  acc[ 1] += wreg * x0.y; \
    acc[ 2] += wreg * x0.z;  acc[ 3] += wreg * x0.w; \
    acc[ 4] += wreg * x1.x;  acc[ 5] += wreg * x1.y; \
    acc[ 6] += wreg * x1.z;  acc[ 7] += wreg * x1.w; \
    acc[ 8] += wreg * x2.x;  acc[ 9] += wreg * x2.y; \
    acc[10] += wreg * x2.z;  acc[11] += wreg * x2.w; \
    acc[12] += wreg * x3.x;  acc[13] += wreg * x3.y; \
    acc[14] += wreg * x3.z;  acc[15] += wreg * x3.w; \
    acc[16] += wreg * x4.x;  acc[17] += wreg * x4.y; \
    acc[18] += wreg * x4.z;  acc[19] += wreg * x4.w; \
    acc[20] += wreg * x5.x;  acc[21] += wreg * x5.y; \
    acc[22] += wreg * x5.z;  acc[23] += wreg * x5.w; }

// grid (chunk, cseg, dtile); 4 waves split the 128-c tile (disjoint W),
// each accumulates all 24 rows; LDS phased combine; streaming partial store.
__global__ __launch_bounds__(256, 2) void subject_gemm(
    const float* __restrict__ x, const float* __restrict__ W,
    const int* __restrict__ ws, float* __restrict__ ws_part)
{
    const int chunk = blockIdx.x;
    if (chunk >= ws[0]) return;
    const int s     = ws[ENT_OFF + chunk * 3 + 0];
    const int start = ws[ENT_OFF + chunk * 3 + 1];
    const int cnt   = ws[ENT_OFF + chunk * 3 + 2];
    const int cbase = blockIdx.y * CSEG;
    const int dbase = blockIdx.z * DTILE;

    // union: xst[128][28] (14 KB) for staging, obuf[24][256] (24 KB) after
    __shared__ float smem[RPC * DTILE];
    float (*xst)[XPAD] = (float(*)[XPAD])smem;
    __shared__ int rowidx[RPC];

    const int t = threadIdx.x;
    if (t < RPC)
        rowidx[t] = (t < cnt) ? ws[PERM_OFF + start + t] : -1;
    __syncthreads();

    // stage x tile (24 rows x 128 c), 2 rows per pass, coalesced
    const int tc  = t & 127;
    const int tr2 = t >> 7;
    #pragma unroll
    for (int r = 0; r < RPC; r += 2) {
        const int rr  = r + tr2;
        const int row = rowidx[rr];
        xst[tc][rr] = (row >= 0) ? x[(size_t)row * IN_CH_K + cbase + tc] : 0.0f;
    }
    __syncthreads();   // drains vmcnt -> asm counts below deterministic

    const int lane = t & 63;
    const int wave = t >> 6;
    const int cs   = wave * WSLICE;
    const int d    = dbase + lane * 4;
    const float* wp = W + (size_t)s * (IN_CH_K * OUT_CH_K)
                        + (size_t)(cbase + cs) * OUT_CH_K + d;

    f4v acc[RPC];
    #pragma unroll
    for (int r = 0; r < RPC; ++r) acc[r] = (f4v){0.f, 0.f, 0.f, 0.f};
    f4v wa0, wa1, wa2, wa3, wb0, wb1, wb2, wb3;

    GLOAD(wa0, wp + 0 * OUT_CH_K);
    GLOAD(wa1, wp + 1 * OUT_CH_K);
    GLOAD(wa2, wp + 2 * OUT_CH_K);
    GLOAD(wa3, wp + 3 * OUT_CH_K);
    GLOAD(wb0, wp + 4 * OUT_CH_K);
    GLOAD(wb1, wp + 5 * OUT_CH_K);
    GLOAD(wb2, wp + 6 * OUT_CH_K);
    GLOAD(wb3, wp + 7 * OUT_CH_K);

    #pragma unroll 1
    for (int cb = 0; cb < WSLICE - 8; cb += 8) {
        WAIT_VM(4);                              // A landed, B in flight
        CSTEP(wa0, cs + cb + 0)
        CSTEP(wa1, cs + cb + 1)
        CSTEP(wa2, cs + cb + 2)
        CSTEP(wa3, cs + cb + 3)
        const float* wn = wp + (size_t)(cb + 8) * OUT_CH_K;
        GLOAD(wa0, wn + 0 * OUT_CH_K);
        GLOAD(wa1, wn + 1 * OUT_CH_K);
        GLOAD(wa2, wn + 2 * OUT_CH_K);
        GLOAD(wa3, wn + 3 * OUT_CH_K);
        WAIT_VM(4);                              // B landed, next-A in flight
        CSTEP(wb0, cs + cb + 4)
        CSTEP(wb1, cs + cb + 5)
        CSTEP(wb2, cs + cb + 6)
        CSTEP(wb3, cs + cb + 7)
        GLOAD(wb0, wn + 4 * OUT_CH_K);
        GLOAD(wb1, wn + 5 * OUT_CH_K);
        GLOAD(wb2, wn + 6 * OUT_CH_K);
        GLOAD(wb3, wn + 7 * OUT_CH_K);
    }
    {   // epilogue: cb = WSLICE-8
        const int cb = WSLICE - 8;
        WAIT_VM(4);
        CSTEP(wa0, cs + cb + 0)
        CSTEP(wa1, cs + cb + 1)
        CSTEP(wa2, cs + cb + 2)
        CSTEP(wa3, cs + cb + 3)
        WAIT_VM(0);
        CSTEP(wb0, cs + cb + 4)
        CSTEP(wb1, cs + cb + 5)
        CSTEP(wb2, cs + cb + 6)
        CSTEP(wb3, cs + cb + 7)
    }

    // ---- cross-wave combine in LDS (reuse smem as obuf[24][256]) ----
    __syncthreads();
    float (*obuf)[DTILE] = (float(*)[DTILE])smem;
    if (wave == 0) {
        #pragma unroll
        for (int r = 0; r < RPC; ++r)
            *(f4v*)&obuf[r][lane * 4] = acc[r];
    }
    __syncthreads();
    #pragma unroll
    for (int w = 1; w < 4; ++w) {
        if (wave == w) {
            #pragma unroll
            for (int r = 0; r < RPC; ++r) {
                f4v v = *(const f4v*)&obuf[r][lane * 4];
                *(f4v*)&obuf[r][lane * 4] = v + acc[r];
            }
        }
        __syncthreads();
    }

    // wave w streams rows 6w..6w+5 into partial[cseg]
    float* pb = ws_part + (size_t)blockIdx.y * (B_ROWS * OUT_CH_K) + d;
    #pragma unroll
    for (int i = 0; i < 6; ++i) {
        const int r = wave * 6 + i;
        const int row = rowidx[r];
        if (row >= 0)
            *(f4v*)(pb + (size_t)row * OUT_CH_K) =
                *(const f4v*)&obuf[r][lane * 4];
    }
}

// out[b,d] = bias[idx[b],d] + sum_k part[k][b][d]
__global__ __launch_bounds__(256) void reduce_parts(
    const int* __restrict__ idx, const float* __restrict__ bias,
    const float* __restrict__ part, float* __restrict__ out)
{
    const int b = blockIdx.x;
    const int s = idx[b];
    const int d = threadIdx.x * 4;
    float4 a = *(const float4*)&bias[(size_t)s * OUT_CH_K + d];
    #pragma unroll
    for (int k = 0; k < CSEGS; ++k) {
        const float4 p = *(const float4*)
            &part[((size_t)k * B_ROWS + b) * OUT_CH_K + d];
        a.x += p.x; a.y += p.y; a.z += p.z; a.w += p.w;
    }
    *(float4*)&out[(size_t)b * OUT_CH_K + d] = a;
}

extern "C" void kernel_launch(void* const* d_in, const int* in_sizes, int n_in,
                              void* d_out, int out_size, void* d_ws, size_t ws_size,
                              hipStream_t stream) {
    const float* x    = (const float*)d_in[0];
    const int*   idx  = (const int*)d_in[1];
    const float* W    = (const float*)d_in[2];
    const float* bias = (const float*)d_in[3];
    float* out = (float*)d_out;
    int* ws = (int*)d_ws;
    float* ws_part = (float*)ws + PART_OFF_F;

    build_groups<<<1, 512, 0, stream>>>(idx, ws);

    dim3 grid(MAX_CHUNKS, CSEGS, DTILES);  // (64,8,4); ~1056 active blocks
    subject_gemm<<<grid, 256, 0, stream>>>(x, W, ws, ws_part);
    reduce_parts<<<B_ROWS, 256, 0, stream>>>(idx, bias, ws_part, out);
}